// Round 3
// baseline (83.964 us; speedup 1.0000x reference)
//
#include <hip/hip_runtime.h>

#define OUT_STRIDE 576   // IN_F(512) + OUT_F(64)

typedef __attribute__((ext_vector_type(8))) short bf16x8;
typedef __attribute__((ext_vector_type(4))) float f32x4;

__device__ inline unsigned short f2bf(float f) {
    unsigned u = __float_as_uint(f);
    u = (u + 0x7FFFu + ((u >> 16) & 1u)) >> 16;   // RNE
    return (unsigned short)u;
}

// ---------------- Kernel P: transpose+convert T [512 k][1024 n] fp32 -> Tb [1024 n][512 k] bf16
__global__ __launch_bounds__(256) void transpose_T_kernel(
    const float* __restrict__ T, unsigned short* __restrict__ Tb)
{
    __shared__ float tt[64][68];
    const int b = blockIdx.x;      // 128 blocks: 8 k-tiles x 16 n-tiles
    const int t = threadIdx.x;
    const int k0 = (b & 7) * 64, n0 = (b >> 3) * 64;
    const int n4 = (t & 15) * 4, kr = t >> 4;
#pragma unroll
    for (int rr = 0; rr < 4; ++rr) {
        const int k = rr * 16 + kr;
        *(float4*)&tt[k][n4] = *(const float4*)(T + (size_t)(k0 + k) * 1024 + n0 + n4);
    }
    __syncthreads();
#pragma unroll
    for (int q = 0; q < 4; ++q) {
        const int g = q * 256 + t;
        const int nn = g >> 4, c = g & 15;
        ushort4 w;
        w.x = f2bf(tt[c * 4 + 0][nn]);
        w.y = f2bf(tt[c * 4 + 1][nn]);
        w.z = f2bf(tt[c * 4 + 2][nn]);
        w.w = f2bf(tt[c * 4 + 3][nn]);
        *(ushort4*)(Tb + (size_t)(n0 + nn) * 512 + k0 + c * 4) = w;
    }
}

// ---------------- Kernel G: M = x @ T via bf16 MFMA 16x16x32 --------------------
// Grid 512 = 32 m-tiles(16) x 16 n-strips(64). 4 waves; wave w does n-subtile w*16.
__global__ __launch_bounds__(256) void gemm_kernel(
    const float* __restrict__ x, const unsigned short* __restrict__ Tb,
    float* __restrict__ M, float* __restrict__ out)
{
    __shared__ unsigned short As[16 * 72];
    __shared__ unsigned short Bs[64 * 72];
    const int t = threadIdx.x;
    const int bx = blockIdx.x & 15, by = blockIdx.x >> 4;
    const int c0 = bx * 64, r0 = by * 16;
    const int lane = t & 63, w = t >> 6;
    const int nb = w * 16;
    const int fl = lane & 15, q8 = (lane >> 4) * 8;
    const int ar = t >> 4, ak4 = (t & 15) * 4;   // A stage: row 0..15, k quad
    const int bn = t >> 3, bk8 = (t & 7) * 8;    // B stage: n 0..31 (+32), k oct

    f32x4 acc = {0.f, 0.f, 0.f, 0.f};

    for (int kc = 0; kc < 512; kc += 64) {
        {
            const float4 u = *(const float4*)(x + (size_t)(r0 + ar) * 512 + kc + ak4);
            ushort4 w0;
            w0.x = f2bf(u.x); w0.y = f2bf(u.y); w0.z = f2bf(u.z); w0.w = f2bf(u.w);
            *(ushort4*)&As[ar * 72 + ak4] = w0;
        }
#pragma unroll
        for (int h = 0; h < 2; ++h) {
            const int n = bn + h * 32;
            *(uint4*)&Bs[n * 72 + bk8] =
                *(const uint4*)(Tb + (size_t)(c0 + n) * 512 + kc + bk8);
        }
        __syncthreads();
        const bf16x8 a0 = *(const bf16x8*)&As[fl * 72 + q8];
        const bf16x8 a1 = *(const bf16x8*)&As[fl * 72 + 32 + q8];
        const bf16x8 b0 = *(const bf16x8*)&Bs[(nb + fl) * 72 + q8];
        const bf16x8 b1 = *(const bf16x8*)&Bs[(nb + fl) * 72 + 32 + q8];
        acc = __builtin_amdgcn_mfma_f32_16x16x32_bf16(a0, b0, acc, 0, 0, 0);
        acc = __builtin_amdgcn_mfma_f32_16x16x32_bf16(a1, b1, acc, 0, 0, 0);
        __syncthreads();
    }
    const int orow = r0 + (lane >> 4) * 4;
#pragma unroll
    for (int r = 0; r < 4; ++r)
        M[(size_t)(orow + r) * 1024 + c0 + nb + fl] = acc[r];

    // ---- epilogue: x passthrough + o_b init to -1 ----
    const int bid = blockIdx.x;    // 0..511
    if (t < 128) {
        const int idx = (bid * 128 + t) * 4;
        const int i = idx >> 9, c = idx & 511;
        *(float4*)(out + (size_t)i * OUT_STRIDE + c) = *(const float4*)(x + idx);
    } else if (t < 192) {
        const int idx = bid * 64 + (t - 128);
        const int i = idx >> 6, o = idx & 63;
        out[(size_t)i * OUT_STRIDE + 512 + o] = -1.0f;
    }
}

// ---------------- Kernel B: symmetric pairwise L1 -> exp -> sum ---------------------
// 528 blocks = unordered pairs of 16-row tiles (ti<=tj). Thread = (4 i-rows, 1 o).
// Off-diagonal blocks also accumulate the j-side via an LDS reduction.
__global__ __launch_bounds__(256, 3) void pairwise_kernel(
    const float* __restrict__ M, float* __restrict__ out)
{
    __shared__ float sj[8 * 1280];   // 40 KB staging; tail 16 KB reused for j-reduction
    const int t = threadIdx.x;
    const int o = t & 63, ig = t >> 6;
    const int b = blockIdx.x;

    // triangular decode: ti such that Start(ti) <= b < Start(ti+1), Start(r)=r*(65-r)/2
    int ti = (int)((65.0f - sqrtf(4225.0f - 8.0f * (float)b)) * 0.5f);
    if (b < ti * (65 - ti) / 2) --ti;
    else if (b >= (ti + 1) * (64 - ti) / 2) ++ti;
    const int st = ti * (65 - ti) / 2;
    const int tj = ti + (b - st);
    const int i0 = ti * 16, j0 = tj * 16;
    const bool diag = (ti == tj);

    float mi[4][16];
#pragma unroll
    for (int r = 0; r < 4; ++r) {
        const float* rp = M + (size_t)(i0 + ig * 4 + r) * 1024 + o * 16;
#pragma unroll
        for (int q = 0; q < 4; ++q) {
            const float4 v = *(const float4*)(rp + q * 4);
            mi[r][q * 4 + 0] = v.x; mi[r][q * 4 + 1] = v.y;
            mi[r][q * 4 + 2] = v.z; mi[r][q * 4 + 3] = v.w;
        }
    }
    float acci[4] = {0.f, 0.f, 0.f, 0.f};
    float accj[16];
#pragma unroll
    for (int j = 0; j < 16; ++j) accj[j] = 0.f;

    const int os = t >> 2, k4 = t & 3;
#pragma unroll
    for (int jb = 0; jb < 16; jb += 8) {
#pragma unroll
        for (int q = 0; q < 8; ++q) {
            const float4 v = *(const float4*)(M + (size_t)(j0 + jb + q) * 1024 + t * 4);
            *(float4*)&sj[q * 1280 + os * 20 + k4 * 4] = v;
        }
        __syncthreads();
#pragma unroll
        for (int q = 0; q < 8; ++q) {
            const float* s = sj + q * 1280 + o * 20;
            float l1[4] = {0.f, 0.f, 0.f, 0.f};
#pragma unroll
            for (int q4 = 0; q4 < 4; ++q4) {
                const float4 v = *(const float4*)(s + q4 * 4);
#pragma unroll
                for (int r = 0; r < 4; ++r) {
                    l1[r] += fabsf(mi[r][q4 * 4 + 0] - v.x);
                    l1[r] += fabsf(mi[r][q4 * 4 + 1] - v.y);
                    l1[r] += fabsf(mi[r][q4 * 4 + 2] - v.z);
                    l1[r] += fabsf(mi[r][q4 * 4 + 3] - v.w);
                }
            }
            float e0 = __expf(-l1[0]), e1 = __expf(-l1[1]);
            float e2 = __expf(-l1[2]), e3 = __expf(-l1[3]);
            acci[0] += e0; acci[1] += e1; acci[2] += e2; acci[3] += e3;
            if (!diag) accj[jb + q] += (e0 + e1) + (e2 + e3);
        }
        __syncthreads();
    }

    // i-side: one atomic per (i,o)
#pragma unroll
    for (int r = 0; r < 4; ++r)
        atomicAdd(out + (size_t)(i0 + ig * 4 + r) * OUT_STRIDE + 512 + o, acci[r]);

    // j-side: reduce accj over the 4 ig groups through LDS, one atomic per (j,o)
    if (!diag) {
#pragma unroll
        for (int j = 0; j < 16; ++j)
            sj[ig * 1024 + j * 64 + o] = accj[j];
        __syncthreads();
#pragma unroll
        for (int p = 0; p < 4; ++p) {
            const int jj = ig * 4 + p;
            const float s = sj[0 * 1024 + jj * 64 + o] + sj[1 * 1024 + jj * 64 + o]
                          + sj[2 * 1024 + jj * 64 + o] + sj[3 * 1024 + jj * 64 + o];
            atomicAdd(out + (size_t)(j0 + jj) * OUT_STRIDE + 512 + o, s);
        }
    }
}

extern "C" void kernel_launch(void* const* d_in, const int* in_sizes, int n_in,
                              void* d_out, int out_size, void* d_ws, size_t ws_size,
                              hipStream_t stream) {
    const float* x = (const float*)d_in[0];
    const float* T = (const float*)d_in[1];
    float* out = (float*)d_out;
    float* M = (float*)d_ws;                                          // 2 MB fp32
    unsigned short* Tb = (unsigned short*)((char*)d_ws + (2 << 20));  // 1 MB bf16

    transpose_T_kernel<<<128, 256, 0, stream>>>(T, Tb);
    gemm_kernel<<<512, 256, 0, stream>>>(x, Tb, M, out);
    pairwise_kernel<<<528, 256, 0, stream>>>(M, out);
}